// Round 11
// baseline (346.355 us; speedup 1.0000x reference)
//
#include <hip/hip_runtime.h>
#include <hip/hip_bf16.h>
#include <math.h>

#define DM    1024
#define SEQL  2048
#define NB    2
#define MTOT  4096   // NB*SEQL
#define NTAB  (SEQL * 64)   // cos/sin table entries (s, d)

typedef __attribute__((ext_vector_type(8))) short short8;
typedef __attribute__((ext_vector_type(4))) short short4v;
typedef __attribute__((ext_vector_type(4))) float float4v;

__device__ __forceinline__ short f2bf(float f) {
  union { float f; unsigned u; } c; c.f = f;
  unsigned r = c.u + 0x7FFFu + ((c.u >> 16) & 1u);  // RNE
  return (short)(r >> 16);
}

// pack two fp32 -> dword of two bf16 (lo=a, hi=b); round-half-up
__device__ __forceinline__ int packbf(float a, float b) {
  union { float f; unsigned u; } ca, cb; ca.f = a; cb.f = b;
  return (int)__builtin_amdgcn_perm(cb.u + 0x8000u, ca.u + 0x8000u, 0x07060302u);
}

__device__ __forceinline__ float bflo(unsigned u) {
  union { unsigned u; float f; } c; c.u = u << 16; return c.f;
}
__device__ __forceinline__ float bfhi(unsigned u) {
  union { unsigned u; float f; } c; c.u = u & 0xFFFF0000u; return c.f;
}

// Converts x + 4 weights fp32->bf16, and builds packed bf16 (cos,sin) tables:
// csq = (cos*sc, sin*sc) with sc = 0.125*log2(e) (Q path), csk = (cos, sin).
__global__ __launch_bounds__(256) void cvt_all(
    const float* __restrict__ x, const float* __restrict__ wq, const float* __restrict__ wk,
    const float* __restrict__ wv, const float* __restrict__ wo,
    const float* __restrict__ cosp, const float* __restrict__ sinp,
    short* __restrict__ xb, short* __restrict__ wqb, short* __restrict__ wkb,
    short* __restrict__ wvb, short* __restrict__ wob,
    unsigned* __restrict__ csq, unsigned* __restrict__ csk) {
  const int n4x = MTOT * DM / 4;        // 1,048,576
  const int n4all = n4x + DM * DM;      // + 4 weights = 2,097,152
  int i = blockIdx.x * 256 + threadIdx.x;
  if (i < n4all) {
    const float* s; short* d; int off;
    if (i < n4x) { s = x; d = xb; off = i; }
    else {
      int j = i - n4x;
      int sel = j >> 18;                // DM*DM/4 = 262144 = 2^18
      off = j & 0x3FFFF;
      s = (sel == 0) ? wq : (sel == 1) ? wk : (sel == 2) ? wv : wo;
      d = (sel == 0) ? wqb : (sel == 1) ? wkb : (sel == 2) ? wvb : wob;
    }
    float4 v = ((const float4*)s)[off];
    short4v o;
    o.x = f2bf(v.x); o.y = f2bf(v.y); o.z = f2bf(v.z); o.w = f2bf(v.w);
    ((short4v*)d)[off] = o;
  } else {
    int j2 = i - n4all;                 // [0, NTAB)
    if (j2 < NTAB) {
      const float sc = 0.18033688011112042f;  // 0.125*log2(e)
      float c = cosp[j2], s = sinp[j2];
      csq[j2] = (unsigned)packbf(c * sc, s * sc);
      csk[j2] = (unsigned)packbf(c, s);
    }
  }
}

// Fused QKV projection v4: NO LDS, NO barriers. All A/B fragments loaded
// directly from global (L2-resident: A slab shared by 24 blocks, B slab by 32).
// Fragment reads are 64B-granule aligned (4 quads x 16B contiguous per row).
// Register global loads get fine-grained compiler vmcnt (not the vmcnt(0)
// barrier drain that pinned every LDS-staged variant at ~45us). 256 thr,
// 128x128 tile, waves decoupled. blockIdx.z: 0/1 -> RoPE store, 2 -> Vt.
__global__ __launch_bounds__(256, 3) void qkv_kernel(
    const short* __restrict__ A,
    const short* __restrict__ B0, const short* __restrict__ B1, const short* __restrict__ B2,
    short* __restrict__ out0, short* __restrict__ out1, short* __restrict__ out2,
    const unsigned* __restrict__ csq, const unsigned* __restrict__ csk)
{
  const int t = threadIdx.x;
  const int w = t >> 6, lane = t & 63;
  const int quad = lane >> 4, l16 = lane & 15;
  const int wm = w >> 1, wn = w & 1;
  const int bm = blockIdx.y * 128, bn = blockIdx.x * 128;

  const short* Bw = (blockIdx.z == 0) ? B0 : ((blockIdx.z == 1) ? B1 : B2);

  // per-lane row bases (fixed across k)
  const short* arow[4];
  const short* brow[4];
#pragma unroll
  for (int mt = 0; mt < 4; ++mt)
    arow[mt] = A  + (size_t)(bm + wm * 64 + mt * 16 + l16) * DM + quad * 8;
#pragma unroll
  for (int nt = 0; nt < 4; ++nt)
    brow[nt] = Bw + (size_t)(bn + wn * 64 + nt * 16 + l16) * DM + quad * 8;

  float4v acc[4][4];
#pragma unroll
  for (int i = 0; i < 4; ++i)
#pragma unroll
    for (int j = 0; j < 4; ++j) { float4v z = {0.f, 0.f, 0.f, 0.f}; acc[i][j] = z; }

#pragma unroll 2
  for (int k0 = 0; k0 < DM; k0 += 32) {
    short8 af[4], bf[4];
#pragma unroll
    for (int mt = 0; mt < 4; ++mt) af[mt] = *(const short8*)(arow[mt] + k0);
#pragma unroll
    for (int nt = 0; nt < 4; ++nt) bf[nt] = *(const short8*)(brow[nt] + k0);
#pragma unroll
    for (int mt = 0; mt < 4; ++mt)
#pragma unroll
      for (int nt = 0; nt < 4; ++nt)
        acc[mt][nt] = __builtin_amdgcn_mfma_f32_16x16x32_bf16(af[mt], bf[nt], acc[mt][nt], 0, 0, 0);
  }

  if (blockIdx.z < 2) {
    // RoPE + bf16 store. Wave col-span is 64 = one head; pair (d, d+32) = (nt, nt+2).
    short* qo = (blockIdx.z == 0) ? out0 : out1;
    const unsigned* tbl = (blockIdx.z == 0) ? csq : csk;
#pragma unroll
    for (int mt = 0; mt < 4; ++mt)
#pragma unroll
      for (int r = 0; r < 4; ++r) {
        int grow = bm + wm * 64 + mt * 16 + quad * 4 + r;
        int s = grow & (SEQL - 1);
        int base = grow * DM + bn + wn * 64;
#pragma unroll
        for (int nt = 0; nt < 2; ++nt) {
          int d1 = nt * 16 + l16;  // 0..31
          float q1 = acc[mt][nt][r], q2 = acc[mt][nt + 2][r];
          unsigned t0 = tbl[s * 64 + d1];
          unsigned t1 = tbl[s * 64 + 32 + d1];
          qo[base + d1]      = f2bf(q1 * bflo(t0) - q2 * bfhi(t0));
          qo[base + 32 + d1] = f2bf(q2 * bflo(t1) + q1 * bfhi(t1));
        }
      }
  } else {
    // V stored transposed: Vt[n][b*S+s], 4 consecutive rows per lane -> 8B stores
    short* vo = out2;
#pragma unroll
    for (int mt = 0; mt < 4; ++mt)
#pragma unroll
      for (int nt = 0; nt < 4; ++nt) {
        int gc = bn + wn * 64 + nt * 16 + l16;
        int g0 = bm + wm * 64 + mt * 16 + quad * 4;
        short4v pk;
#pragma unroll
        for (int r = 0; r < 4; ++r) pk[r] = f2bf(acc[mt][nt][r]);
        *(short4v*)&vo[(size_t)gc * MTOT + g0] = pk;
      }
  }
}

// Flash attention v8: NO K/V LDS staging, NO k-loop barriers. K and Vt
// fragments loaded directly from global (L2: 256KB/head slabs, 64B-granule
// aligned patterns) with fine-grained compiler vmcnt. 512-thread blocks, pair
// (i,31-i) -> uniform 17 iters; 8 waves split the K-dimension (g=0: k 0..63,
// g=1: 64..127); fixed m=0 (scale+log2e folded into Q). P^T via wave-PRIVATE
// LDS strips (same-wave ds_write->ds_read, lgkmcnt only). Partials merged in
// a 2-barrier epilogue; normalizer transposed via __shfl.
__global__ __launch_bounds__(512, 4) void attn_kernel(
    const short* __restrict__ Q, const short* __restrict__ K,
    const short* __restrict__ Vt, short* __restrict__ O)
{
  __shared__ short smem[18432];        // 36 KB: 8 wave-private P strips (epilogue reuses)
  const int t = threadIdx.x;
  const int wid = t >> 6, lane = t & 63;
  const int quad = lane >> 4, l16 = lane & 15;
  const int g = wid >> 2;              // k-half group
  const int qg = wid & 3;              // q-row group (16 rows)
  short* Pl = smem + wid * (2 * 16 * 72);  // [2 tiles][16 q][72]
  const int qtA = blockIdx.x, qtB = 31 - blockIdx.x;
  const int bh = blockIdx.y, b = bh >> 4, h = bh & 15;
  const int rowbase = b * SEQL, colbase = h * 64;
  const int nktA = (qtA >> 1) + 1, nktB = (qtB >> 1) + 1;
  const int qA = qtA * 64 + qg * 16 + l16;
  const int qB = qtB * 64 + qg * 16 + l16;

  short8 aqA[2], aqB[2];
#pragma unroll
  for (int kk = 0; kk < 2; ++kk) {
    aqA[kk] = *(const short8*)&Q[(size_t)(rowbase + qA) * DM + colbase + kk * 32 + quad * 8];
    aqB[kk] = *(const short8*)&Q[(size_t)(rowbase + qB) * DM + colbase + kk * 32 + quad * 8];
  }

  // per-lane row bases
  const short* krow = K + (size_t)(rowbase + (g * 4) * 16 + l16) * DM + colbase + quad * 8;
  const short* vrow[4];
#pragma unroll
  for (int dt = 0; dt < 4; ++dt)
    vrow[dt] = Vt + (size_t)(colbase + dt * 16 + l16) * MTOT + rowbase + g * 64 + quad * 8;

  float4v oA[4], oB[4];
#pragma unroll
  for (int j = 0; j < 4; ++j) { float4v z = {0.f, 0.f, 0.f, 0.f}; oA[j] = z; oB[j] = z; }
  float lA = 0.f, lB = 0.f;            // per-lane partial row-sum, indexed by q = l16

  for (int kt = 0; kt < nktB; ++kt) {
    const bool actA = (kt < nktA);
    const bool diagA = (kt == nktA - 1), diagB = (kt == nktB - 1);

    // --- S^T = K Q^T on this wave's 4 nt-subtiles; exp2; P^T -> strip (b64) ---
#pragma unroll
    for (int ntl = 0; ntl < 4; ++ntl) {
      const int nt = g * 4 + ntl;
      const short* kp = krow + (size_t)(kt * 128 + ntl * 16) * DM;
      short8 bk0 = *(const short8*)(kp);
      short8 bk1 = *(const short8*)(kp + 32);
      const int kb = kt * 128 + nt * 16 + quad * 4;
      float4v zz = {0.f, 0.f, 0.f, 0.f};
      float4v sB = __builtin_amdgcn_mfma_f32_16x16x32_bf16(bk0, aqB[0], zz, 0, 0, 0);
      sB = __builtin_amdgcn_mfma_f32_16x16x32_bf16(bk1, aqB[1], sB, 0, 0, 0);
      float pb[4];
#pragma unroll
      for (int r = 0; r < 4; ++r) {
        float pv = (diagB && (kb + r > qB)) ? 0.f : __builtin_amdgcn_exp2f(sB[r]);
        lB += pv; pb[r] = pv;
      }
      *(int2*)&Pl[1 * 16 * 72 + l16 * 72 + ntl * 16 + quad * 4] =
          make_int2(packbf(pb[0], pb[1]), packbf(pb[2], pb[3]));
      if (actA) {
        float4v sA = __builtin_amdgcn_mfma_f32_16x16x32_bf16(bk0, aqA[0], zz, 0, 0, 0);
        sA = __builtin_amdgcn_mfma_f32_16x16x32_bf16(bk1, aqA[1], sA, 0, 0, 0);
        float pa[4];
#pragma unroll
        for (int r = 0; r < 4; ++r) {
          float pv = (diagA && (kb + r > qA)) ? 0.f : __builtin_amdgcn_exp2f(sA[r]);
          lA += pv; pa[r] = pv;
        }
        *(int2*)&Pl[0 * 16 * 72 + l16 * 72 + ntl * 16 + quad * 4] =
            make_int2(packbf(pa[0], pa[1]), packbf(pa[2], pa[3]));
      }
    }

    // --- O += P V over this wave's 64-k half; V frags direct from global ---
#pragma unroll
    for (int kk = 0; kk < 2; ++kk) {
      short8 apB = *(const short8*)&Pl[1 * 16 * 72 + l16 * 72 + kk * 32 + quad * 8];
      short8 apA;
      if (actA) apA = *(const short8*)&Pl[0 * 16 * 72 + l16 * 72 + kk * 32 + quad * 8];
#pragma unroll
      for (int dt = 0; dt < 4; ++dt) {
        short8 bv = *(const short8*)(vrow[dt] + kt * 128 + kk * 32);
        oB[dt] = __builtin_amdgcn_mfma_f32_16x16x32_bf16(apB, bv, oB[dt], 0, 0, 0);
        if (actA) oA[dt] = __builtin_amdgcn_mfma_f32_16x16x32_bf16(apA, bv, oA[dt], 0, 0, 0);
      }
    }
  }

  lA += __shfl_xor(lA, 16); lA += __shfl_xor(lA, 32);
  lB += __shfl_xor(lB, 16); lB += __shfl_xor(lB, 32);

  __syncthreads();
  float* Ored = (float*)smem;                   // [2 tiles][4 qg][16 q][66]
  float* Lred = (float*)smem + 8448;            // [2 tiles][4 qg][16 q]
  if (g == 1) {
#pragma unroll
    for (int tile = 0; tile < 2; ++tile) {
      const float4v* src = (tile == 0) ? oA : oB;
      const int base = ((tile * 4 + qg) * 16) * 66;
#pragma unroll
      for (int dt = 0; dt < 4; ++dt)
#pragma unroll
        for (int r = 0; r < 4; ++r)
          Ored[base + (quad * 4 + r) * 66 + dt * 16 + l16] = src[dt][r];
    }
    if (lane < 16) {
      Lred[(0 * 4 + qg) * 16 + l16] = lA;
      Lred[(1 * 4 + qg) * 16 + l16] = lB;
    }
  }
  __syncthreads();
  if (g == 0) {
    const float tA = lA + Lred[(0 * 4 + qg) * 16 + l16];
    const float tB = lB + Lred[(1 * 4 + qg) * 16 + l16];
    float iAr[4], iBr[4];
#pragma unroll
    for (int r = 0; r < 4; ++r) {
      iAr[r] = 1.f / __shfl(tA, quad * 4 + r);
      iBr[r] = 1.f / __shfl(tB, quad * 4 + r);
    }
#pragma unroll
    for (int tile = 0; tile < 2; ++tile) {
      const float4v* src = (tile == 0) ? oA : oB;
      const int qt = (tile == 0) ? qtA : qtB;
      const int base = ((tile * 4 + qg) * 16) * 66;
#pragma unroll
      for (int dt = 0; dt < 4; ++dt)
#pragma unroll
        for (int r = 0; r < 4; ++r) {
          float v = src[dt][r] + Ored[base + (quad * 4 + r) * 66 + dt * 16 + l16];
          int grow = rowbase + qt * 64 + qg * 16 + quad * 4 + r;
          int gcol = colbase + dt * 16 + l16;
          O[(size_t)grow * DM + gcol] = f2bf(v * ((tile == 0) ? iAr[r] : iBr[r]));
        }
    }
  }
}

// Output projection v3: NO LDS, NO barriers — direct L2 fragment loads.
// out = attn x Wo^T, 128m x 64n tiles, fp32 store.
__global__ __launch_bounds__(256, 3) void gemm_out(
    const short* __restrict__ A, const short* __restrict__ B,
    float* __restrict__ out)
{
  const int t = threadIdx.x;
  const int w = t >> 6, lane = t & 63;
  const int quad = lane >> 4, l16 = lane & 15;
  const int wm = w >> 1, wn = w & 1;
  const int bm = blockIdx.y * 128, bn = blockIdx.x * 64;

  const short* arow[4];
  const short* brow[2];
#pragma unroll
  for (int mt = 0; mt < 4; ++mt)
    arow[mt] = A + (size_t)(bm + wm * 64 + mt * 16 + l16) * DM + quad * 8;
#pragma unroll
  for (int nt = 0; nt < 2; ++nt)
    brow[nt] = B + (size_t)(bn + wn * 32 + nt * 16 + l16) * DM + quad * 8;

  float4v acc[4][2];
#pragma unroll
  for (int i = 0; i < 4; ++i)
#pragma unroll
    for (int j = 0; j < 2; ++j) { float4v z = {0.f, 0.f, 0.f, 0.f}; acc[i][j] = z; }

#pragma unroll 2
  for (int k0 = 0; k0 < DM; k0 += 32) {
    short8 af[4], bf[2];
#pragma unroll
    for (int mt = 0; mt < 4; ++mt) af[mt] = *(const short8*)(arow[mt] + k0);
#pragma unroll
    for (int nt = 0; nt < 2; ++nt) bf[nt] = *(const short8*)(brow[nt] + k0);
#pragma unroll
    for (int mt = 0; mt < 4; ++mt)
#pragma unroll
      for (int nt = 0; nt < 2; ++nt)
        acc[mt][nt] = __builtin_amdgcn_mfma_f32_16x16x32_bf16(af[mt], bf[nt], acc[mt][nt], 0, 0, 0);
  }

#pragma unroll
  for (int mt = 0; mt < 4; ++mt)
#pragma unroll
    for (int nt = 0; nt < 2; ++nt)
#pragma unroll
      for (int r = 0; r < 4; ++r) {
        int grow = bm + wm * 64 + mt * 16 + quad * 4 + r;
        int gcol = bn + wn * 32 + nt * 16 + l16;
        out[(size_t)grow * DM + gcol] = acc[mt][nt][r];
      }
}

extern "C" void kernel_launch(void* const* d_in, const int* in_sizes, int n_in,
                              void* d_out, int out_size, void* d_ws, size_t ws_size,
                              hipStream_t stream) {
  const float* x    = (const float*)d_in[0];
  const float* cosp = (const float*)d_in[1];
  const float* sinp = (const float*)d_in[2];
  const float* Wq   = (const float*)d_in[3];
  const float* Wk   = (const float*)d_in[4];
  const float* Wv   = (const float*)d_in[5];
  const float* Wo   = (const float*)d_in[6];

  char* ws = (char*)d_ws;
  const size_t XB = (size_t)MTOT * DM * 2;  // 8 MB
  const size_t WB = (size_t)DM * DM * 2;    // 2 MB
  short* xb    = (short*)(ws);
  short* wqb   = (short*)(ws + XB);
  short* wkb   = (short*)(ws + XB + 1 * WB);
  short* wvb   = (short*)(ws + XB + 2 * WB);
  short* wob   = (short*)(ws + XB + 3 * WB);
  short* Qb    = (short*)(ws + XB + 4 * WB);
  short* Kb    = (short*)(ws + XB + 4 * WB + XB);
  short* Vtb   = (short*)(ws + XB + 4 * WB + 2 * XB);
  unsigned* csq = (unsigned*)(ws + XB + 4 * WB + 3 * XB);            // 512 KB
  unsigned* csk = (unsigned*)(ws + XB + 4 * WB + 3 * XB + NTAB * 4); // 512 KB
  short* attnb = xb;  // x dead after QKV GEMMs; reuse its slot

  const int ntot = (MTOT * DM + 4 * DM * DM) / 4 + NTAB;  // 2,228,224
  hipLaunchKernelGGL(cvt_all, dim3((ntot + 255) / 256), dim3(256), 0, stream,
                     x, Wq, Wk, Wv, Wo, cosp, sinp, xb, wqb, wkb, wvb, wob, csq, csk);

  hipLaunchKernelGGL(qkv_kernel, dim3(DM / 128, MTOT / 128, 3), dim3(256), 0, stream,
                     xb, wqb, wkb, wvb, Qb, Kb, Vtb, csq, csk);

  hipLaunchKernelGGL(attn_kernel, dim3(16, NB * 16), dim3(512), 0, stream,
                     Qb, Kb, Vtb, attnb);

  hipLaunchKernelGGL(gemm_out, dim3(DM / 64, MTOT / 128), dim3(256), 0, stream,
                     attnb, wob, (float*)d_out);
}

// Round 12
// 181.121 us; speedup vs baseline: 1.9123x; 1.9123x over previous
//
#include <hip/hip_runtime.h>
#include <hip/hip_bf16.h>
#include <math.h>

#define DM    1024
#define SEQL  2048
#define NB    2
#define MTOT  4096   // NB*SEQL

typedef __attribute__((ext_vector_type(8))) short short8;
typedef __attribute__((ext_vector_type(4))) short short4v;
typedef __attribute__((ext_vector_type(4))) float float4v;

// async global->LDS, 16B per lane; LDS dest is wave-uniform base (+ lane*16 implicit)
#define GLDS16(g, l) __builtin_amdgcn_global_load_lds( \
    (const __attribute__((address_space(1))) void*)(g), \
    (__attribute__((address_space(3))) void*)(l), 16, 0, 0)

__device__ __forceinline__ short f2bf(float f) {
  union { float f; unsigned u; } c; c.f = f;
  unsigned r = c.u + 0x7FFFu + ((c.u >> 16) & 1u);  // RNE
  return (short)(r >> 16);
}

// pack two fp32 -> dword of two bf16 (lo=a, hi=b); round-half-up (cheap, P>=0)
__device__ __forceinline__ int packbf(float a, float b) {
  union { float f; unsigned u; } ca, cb; ca.f = a; cb.f = b;
  return (int)__builtin_amdgcn_perm(cb.u + 0x8000u, ca.u + 0x8000u, 0x07060302u);
}

// One launch converting x + 4 weights fp32->bf16.
__global__ __launch_bounds__(256) void cvt_all(
    const float* __restrict__ x, const float* __restrict__ wq, const float* __restrict__ wk,
    const float* __restrict__ wv, const float* __restrict__ wo,
    short* __restrict__ xb, short* __restrict__ wqb, short* __restrict__ wkb,
    short* __restrict__ wvb, short* __restrict__ wob) {
  const int n4x = MTOT * DM / 4;        // 1,048,576
  int i = blockIdx.x * 256 + threadIdx.x;
  const float* s; short* d; int off;
  if (i < n4x) { s = x; d = xb; off = i; }
  else {
    int j = i - n4x;
    int sel = j >> 18;                  // DM*DM/4 = 262144 = 2^18
    off = j & 0x3FFFF;
    s = (sel == 0) ? wq : (sel == 1) ? wk : (sel == 2) ? wv : wo;
    d = (sel == 0) ? wqb : (sel == 1) ? wkb : (sel == 2) ? wvb : wob;
  }
  float4 v = ((const float4*)s)[off];
  short4v o;
  o.x = f2bf(v.x); o.y = f2bf(v.y); o.z = f2bf(v.z); o.w = f2bf(v.w);
  ((short4v*)d)[off] = o;
}

// Fused QKV projection, BK=32, ping-pong double-buffered staging.
// blockIdx.z picks Wq/Wk/Wv; z<2 -> RoPE bf16 store (z==0 folds 0.125*log2e
// attention scale into Q), z==2 -> transposed Vt store.
__global__ __launch_bounds__(256, 3) void qkv_kernel(
    const short* __restrict__ A,
    const short* __restrict__ B0, const short* __restrict__ B1, const short* __restrict__ B2,
    short* __restrict__ out0, short* __restrict__ out1, short* __restrict__ out2,
    const float* __restrict__ cosp, const float* __restrict__ sinp)
{
  __shared__ short As[2][128 * 32];
  __shared__ short Bs[2][128 * 32];
  const int t = threadIdx.x;
  const int w = t >> 6, lane = t & 63;
  const int quad = lane >> 4, l16 = lane & 15;
  const int wm = w >> 1, wn = w & 1;
  const int bm = blockIdx.y * 128, bn = blockIdx.x * 128;

  const short* Bw = (blockIdx.z == 0) ? B0 : ((blockIdx.z == 1) ? B1 : B2);

  float4v acc[4][4];
#pragma unroll
  for (int i = 0; i < 4; ++i)
#pragma unroll
    for (int j = 0; j < 4; ++j) { float4v z = {0.f, 0.f, 0.f, 0.f}; acc[i][j] = z; }

  auto stage = [&](int k0, int p) {
#pragma unroll
    for (int i = 0; i < 2; ++i) {
      const int row = (i * 256 + t) >> 2, kc = (i * 256 + t) & 3;
      GLDS16(A  + (size_t)(bm + row) * DM + k0 + kc * 8, &As[p][(i * 256 + w * 64) * 8]);
      GLDS16(Bw + (size_t)(bn + row) * DM + k0 + kc * 8, &Bs[p][(i * 256 + w * 64) * 8]);
    }
  };

  stage(0, 0);
  for (int ki = 0; ki < 32; ++ki) {
    const int p = ki & 1;
    __syncthreads();
    if (ki < 31) stage((ki + 1) * 32, p ^ 1);
    short8 af[4], bf[4];
#pragma unroll
    for (int mt = 0; mt < 4; ++mt) af[mt] = *(const short8*)&As[p][(wm * 64 + mt * 16 + l16) * 32 + quad * 8];
#pragma unroll
    for (int nt = 0; nt < 4; ++nt) bf[nt] = *(const short8*)&Bs[p][(wn * 64 + nt * 16 + l16) * 32 + quad * 8];
#pragma unroll
    for (int mt = 0; mt < 4; ++mt)
#pragma unroll
      for (int nt = 0; nt < 4; ++nt)
        acc[mt][nt] = __builtin_amdgcn_mfma_f32_16x16x32_bf16(af[mt], bf[nt], acc[mt][nt], 0, 0, 0);
  }

  if (blockIdx.z < 2) {
    short* qo = (blockIdx.z == 0) ? out0 : out1;
    const float sc = (blockIdx.z == 0) ? 0.18033688011112042f : 1.0f;  // 0.125*log2(e) for Q
#pragma unroll
    for (int mt = 0; mt < 4; ++mt)
#pragma unroll
      for (int r = 0; r < 4; ++r) {
        int grow = bm + wm * 64 + mt * 16 + quad * 4 + r;
        int s = grow & (SEQL - 1);
        int base = grow * DM + bn + wn * 64;
#pragma unroll
        for (int nt = 0; nt < 2; ++nt) {
          int d1 = nt * 16 + l16;  // 0..31
          float q1 = acc[mt][nt][r], q2 = acc[mt][nt + 2][r];
          float c1 = cosp[s * 64 + d1] * sc,      s1 = sinp[s * 64 + d1] * sc;
          float c2 = cosp[s * 64 + 32 + d1] * sc, s2 = sinp[s * 64 + 32 + d1] * sc;
          qo[base + d1]      = f2bf(q1 * c1 - q2 * s1);
          qo[base + 32 + d1] = f2bf(q2 * c2 + q1 * s2);
        }
      }
  } else {
    short* vo = out2;
#pragma unroll
    for (int mt = 0; mt < 4; ++mt)
#pragma unroll
      for (int nt = 0; nt < 4; ++nt) {
        int gc = bn + wn * 64 + nt * 16 + l16;
        int g0 = bm + wm * 64 + mt * 16 + quad * 4;
        short4v pk;
#pragma unroll
        for (int r = 0; r < 4; ++r) pk[r] = f2bf(acc[mt][nt][r]);
        *(short4v*)&vo[(size_t)gc * MTOT + g0] = pk;
      }
  }
}

// Flash attention v7b: 512-thread blocks, pair (i,31-i) -> uniform 17 iters.
// 8 waves split the K-DIMENSION of each staged 128-k tile (g=0: k 0..63,
// g=1: k 64..127); fixed m=0 makes the k accumulation a plain sum, so groups
// hold independent O/lsum partials merged in the epilogue via LDS.
// S^T = mfma(K,Q): lane's lsum is for q=l16. PV = mfma(P,V): lane's O rows are
// q=quad*4+r -> normalizer transposed via __shfl in the epilogue.
__global__ __launch_bounds__(512, 4) void attn_kernel(
    const short* __restrict__ Q, const short* __restrict__ K,
    const short* __restrict__ Vt, short* __restrict__ O)
{
  __shared__ short smem[34816];        // 68 KB: Ks 16K | Vs 16K | P strips 36K
  short* Ks = smem;                    // [128 n][8 chunks], xor-swizzled
  short* Vs = smem + 8192;             // [64 d][16 chunks], xor-swizzled
  const int t = threadIdx.x;
  const int wid = t >> 6, lane = t & 63;
  const int quad = lane >> 4, l16 = lane & 15;
  const int g = wid >> 2;              // k-half group
  const int qg = wid & 3;              // q-row group (16 rows)
  short* Pl = smem + 16384 + wid * (2 * 16 * 72);  // per-wave strips [2 tiles][16 q][72]
  const int qtA = blockIdx.x, qtB = 31 - blockIdx.x;
  const int bh = blockIdx.y, b = bh >> 4, h = bh & 15;
  const int rowbase = b * SEQL, colbase = h * 64;
  const int nktA = (qtA >> 1) + 1, nktB = (qtB >> 1) + 1;
  const int qA = qtA * 64 + qg * 16 + l16;
  const int qB = qtB * 64 + qg * 16 + l16;

  short8 aqA[2], aqB[2];
#pragma unroll
  for (int kk = 0; kk < 2; ++kk) {
    aqA[kk] = *(const short8*)&Q[(size_t)(rowbase + qA) * DM + colbase + kk * 32 + quad * 8];
    aqB[kk] = *(const short8*)&Q[(size_t)(rowbase + qB) * DM + colbase + kk * 32 + quad * 8];
  }

  float4v oA[4], oB[4];
#pragma unroll
  for (int j = 0; j < 4; ++j) { float4v z = {0.f, 0.f, 0.f, 0.f}; oA[j] = z; oB[j] = z; }
  float lA = 0.f, lB = 0.f;            // per-lane partial row-sum, indexed by q = l16

  for (int kt = 0; kt < nktB; ++kt) {
    {
      const short* Kbase = K + (size_t)(rowbase + kt * 128) * DM + colbase;
      const short* Vbase = Vt + (size_t)colbase * MTOT + rowbase + kt * 128;
#pragma unroll
      for (int j = 0; j < 2; ++j) {
        int i = j * 512 + t;
        int n = i >> 3, c = (i & 7) ^ (n & 7);
        GLDS16(Kbase + (size_t)n * DM + c * 8, Ks + (j * 512 + wid * 64) * 8);
      }
#pragma unroll
      for (int j = 0; j < 2; ++j) {
        int i = j * 512 + t;
        int d = i >> 4, c = (i & 15) ^ (d & 7);
        GLDS16(Vbase + (size_t)d * MTOT + c * 8, Vs + (j * 512 + wid * 64) * 8);
      }
    }
    __syncthreads();
    const bool actA = (kt < nktA);
    const bool diagA = (kt == nktA - 1), diagB = (kt == nktB - 1);

#pragma unroll
    for (int ntl = 0; ntl < 4; ++ntl) {
      const int nt = g * 4 + ntl;
      const int n = nt * 16 + l16;
      short8 bk0 = *(const short8*)&Ks[(n * 8 + (quad ^ (n & 7))) * 8];
      short8 bk1 = *(const short8*)&Ks[(n * 8 + ((4 + quad) ^ (n & 7))) * 8];
      const int kb = kt * 128 + nt * 16 + quad * 4;
      float4v zz = {0.f, 0.f, 0.f, 0.f};
      float4v sB = __builtin_amdgcn_mfma_f32_16x16x32_bf16(bk0, aqB[0], zz, 0, 0, 0);
      sB = __builtin_amdgcn_mfma_f32_16x16x32_bf16(bk1, aqB[1], sB, 0, 0, 0);
      float pb[4];
#pragma unroll
      for (int r = 0; r < 4; ++r) {
        float pv = (diagB && (kb + r > qB)) ? 0.f : __builtin_amdgcn_exp2f(sB[r]);
        lB += pv; pb[r] = pv;
      }
      *(int2*)&Pl[1 * 16 * 72 + l16 * 72 + ntl * 16 + quad * 4] =
          make_int2(packbf(pb[0], pb[1]), packbf(pb[2], pb[3]));
      if (actA) {
        float4v sA = __builtin_amdgcn_mfma_f32_16x16x32_bf16(bk0, aqA[0], zz, 0, 0, 0);
        sA = __builtin_amdgcn_mfma_f32_16x16x32_bf16(bk1, aqA[1], sA, 0, 0, 0);
        float pa[4];
#pragma unroll
        for (int r = 0; r < 4; ++r) {
          float pv = (diagA && (kb + r > qA)) ? 0.f : __builtin_amdgcn_exp2f(sA[r]);
          lA += pv; pa[r] = pv;
        }
        *(int2*)&Pl[0 * 16 * 72 + l16 * 72 + ntl * 16 + quad * 4] =
            make_int2(packbf(pa[0], pa[1]), packbf(pa[2], pa[3]));
      }
    }

#pragma unroll
    for (int kk = 0; kk < 2; ++kk) {
      short8 apB = *(const short8*)&Pl[1 * 16 * 72 + l16 * 72 + kk * 32 + quad * 8];
      short8 apA;
      if (actA) apA = *(const short8*)&Pl[0 * 16 * 72 + l16 * 72 + kk * 32 + quad * 8];
      const int c0 = g * 8 + kk * 4 + quad;
#pragma unroll
      for (int dt = 0; dt < 4; ++dt) {
        const int d = dt * 16 + l16;
        short8 bv = *(const short8*)&Vs[(d * 16 + (c0 ^ (d & 7))) * 8];
        oB[dt] = __builtin_amdgcn_mfma_f32_16x16x32_bf16(apB, bv, oB[dt], 0, 0, 0);
        if (actA) oA[dt] = __builtin_amdgcn_mfma_f32_16x16x32_bf16(apA, bv, oA[dt], 0, 0, 0);
      }
    }
    __syncthreads();
  }

  lA += __shfl_xor(lA, 16); lA += __shfl_xor(lA, 32);
  lB += __shfl_xor(lB, 16); lB += __shfl_xor(lB, 32);

  __syncthreads();
  float* Ored = (float*)smem;                   // [2 tiles][4 qg][16 q][66]
  float* Lred = (float*)smem + 8448;            // [2 tiles][4 qg][16 q]
  if (g == 1) {
#pragma unroll
    for (int tile = 0; tile < 2; ++tile) {
      const float4v* src = (tile == 0) ? oA : oB;
      const int base = ((tile * 4 + qg) * 16) * 66;
#pragma unroll
      for (int dt = 0; dt < 4; ++dt)
#pragma unroll
        for (int r = 0; r < 4; ++r)
          Ored[base + (quad * 4 + r) * 66 + dt * 16 + l16] = src[dt][r];
    }
    if (lane < 16) {
      Lred[(0 * 4 + qg) * 16 + l16] = lA;
      Lred[(1 * 4 + qg) * 16 + l16] = lB;
    }
  }
  __syncthreads();
  if (g == 0) {
    const float tA = lA + Lred[(0 * 4 + qg) * 16 + l16];
    const float tB = lB + Lred[(1 * 4 + qg) * 16 + l16];
    float iAr[4], iBr[4];
#pragma unroll
    for (int r = 0; r < 4; ++r) {
      iAr[r] = 1.f / __shfl(tA, quad * 4 + r);
      iBr[r] = 1.f / __shfl(tB, quad * 4 + r);
    }
#pragma unroll
    for (int tile = 0; tile < 2; ++tile) {
      const float4v* src = (tile == 0) ? oA : oB;
      const int qt = (tile == 0) ? qtA : qtB;
      const int base = ((tile * 4 + qg) * 16) * 66;
#pragma unroll
      for (int dt = 0; dt < 4; ++dt)
#pragma unroll
        for (int r = 0; r < 4; ++r) {
          float v = src[dt][r] + Ored[base + (quad * 4 + r) * 66 + dt * 16 + l16];
          int grow = rowbase + qt * 64 + qg * 16 + quad * 4 + r;
          int gcol = colbase + dt * 16 + l16;
          O[(size_t)grow * DM + gcol] = f2bf(v * ((tile == 0) ? iAr[r] : iBr[r]));
        }
    }
  }
}

// Output projection: out = attn x Wo^T, 128m x 64n tiles (512 blocks), fp32 store.
__global__ __launch_bounds__(256, 2) void gemm_out(
    const short* __restrict__ A, const short* __restrict__ B,
    float* __restrict__ out)
{
  __shared__ short As[2][128 * 32];
  __shared__ short Bs[2][64 * 32];
  const int t = threadIdx.x;
  const int w = t >> 6, lane = t & 63;
  const int quad = lane >> 4, l16 = lane & 15;
  const int wm = w >> 1, wn = w & 1;
  const int bm = blockIdx.y * 128, bn = blockIdx.x * 64;

  float4v acc[4][2];
#pragma unroll
  for (int i = 0; i < 4; ++i)
#pragma unroll
    for (int j = 0; j < 2; ++j) { float4v z = {0.f, 0.f, 0.f, 0.f}; acc[i][j] = z; }

  auto stage = [&](int k0, int p) {
#pragma unroll
    for (int i = 0; i < 2; ++i) {
      const int row = (i * 256 + t) >> 2, kc = (i * 256 + t) & 3;
      GLDS16(A + (size_t)(bm + row) * DM + k0 + kc * 8, &As[p][(i * 256 + w * 64) * 8]);
    }
    {
      const int row = t >> 2, kc = t & 3;
      GLDS16(B + (size_t)(bn + row) * DM + k0 + kc * 8, &Bs[p][(w * 64) * 8]);
    }
  };

  stage(0, 0);
  for (int ki = 0; ki < 32; ++ki) {
    const int p = ki & 1;
    __syncthreads();
    if (ki < 31) stage((ki + 1) * 32, p ^ 1);
    short8 af[4], bf[2];
#pragma unroll
    for (int mt = 0; mt < 4; ++mt) af[mt] = *(const short8*)&As[p][(wm * 64 + mt * 16 + l16) * 32 + quad * 8];
#pragma unroll
    for (int nt = 0; nt < 2; ++nt) bf[nt] = *(const short8*)&Bs[p][(wn * 32 + nt * 16 + l16) * 32 + quad * 8];
#pragma unroll
    for (int mt = 0; mt < 4; ++mt)
#pragma unroll
      for (int nt = 0; nt < 2; ++nt)
        acc[mt][nt] = __builtin_amdgcn_mfma_f32_16x16x32_bf16(af[mt], bf[nt], acc[mt][nt], 0, 0, 0);
  }

#pragma unroll
  for (int mt = 0; mt < 4; ++mt)
#pragma unroll
    for (int nt = 0; nt < 2; ++nt)
#pragma unroll
      for (int r = 0; r < 4; ++r) {
        int grow = bm + wm * 64 + mt * 16 + quad * 4 + r;
        int gcol = bn + wn * 32 + nt * 16 + l16;
        out[(size_t)grow * DM + gcol] = acc[mt][nt][r];
      }
}

extern "C" void kernel_launch(void* const* d_in, const int* in_sizes, int n_in,
                              void* d_out, int out_size, void* d_ws, size_t ws_size,
                              hipStream_t stream) {
  const float* x    = (const float*)d_in[0];
  const float* cosp = (const float*)d_in[1];
  const float* sinp = (const float*)d_in[2];
  const float* Wq   = (const float*)d_in[3];
  const float* Wk   = (const float*)d_in[4];
  const float* Wv   = (const float*)d_in[5];
  const float* Wo   = (const float*)d_in[6];

  char* ws = (char*)d_ws;
  const size_t XB = (size_t)MTOT * DM * 2;  // 8 MB
  const size_t WB = (size_t)DM * DM * 2;    // 2 MB
  short* xb    = (short*)(ws);
  short* wqb   = (short*)(ws + XB);
  short* wkb   = (short*)(ws + XB + 1 * WB);
  short* wvb   = (short*)(ws + XB + 2 * WB);
  short* wob   = (short*)(ws + XB + 3 * WB);
  short* Qb    = (short*)(ws + XB + 4 * WB);
  short* Kb    = (short*)(ws + XB + 4 * WB + XB);
  short* Vtb   = (short*)(ws + XB + 4 * WB + 2 * XB);
  short* attnb = xb;  // x dead after QKV GEMMs; reuse its slot

  const int n4tot = (MTOT * DM + 4 * DM * DM) / 4;  // 2,097,152
  hipLaunchKernelGGL(cvt_all, dim3(n4tot / 256), dim3(256), 0, stream,
                     x, Wq, Wk, Wv, Wo, xb, wqb, wkb, wvb, wob);

  hipLaunchKernelGGL(qkv_kernel, dim3(DM / 128, MTOT / 128, 3), dim3(256), 0, stream,
                     xb, wqb, wkb, wvb, Qb, Kb, Vtb, cosp, sinp);

  hipLaunchKernelGGL(attn_kernel, dim3(16, NB * 16), dim3(512), 0, stream,
                     Qb, Kb, Vtb, attnb);

  hipLaunchKernelGGL(gemm_out, dim3(DM / 64, MTOT / 128), dim3(256), 0, stream,
                     attnb, wob, (float*)d_out);
}